// Round 1
// baseline (372.241 us; speedup 1.0000x reference)
//
#include <hip/hip_runtime.h>
#include <stdint.h>

#define S_LEN 2048
#define HEADS 16
#define DIM   64
// bh = b*HEADS + h, BH = 32. S*D = 1<<17. H*S*D = 1<<21.

typedef float  f4v  __attribute__((ext_vector_type(4)));
typedef float  f16v __attribute__((ext_vector_type(16)));
typedef short  s8v  __attribute__((ext_vector_type(8)));
typedef unsigned int   u4v  __attribute__((ext_vector_type(4)));
typedef unsigned short us4v __attribute__((ext_vector_type(4)));

__device__ __forceinline__ unsigned short f2bf(float f) {
  unsigned int u = __float_as_uint(f);
  u += 0x7fffu + ((u >> 16) & 1u);   // round-to-nearest-even
  return (unsigned short)(u >> 16);
}
__device__ __forceinline__ float bf2f(unsigned short h) {
  return __uint_as_float(((unsigned int)h) << 16);
}
__device__ __forceinline__ unsigned int pk2(float e0, float e1) {
  return (unsigned int)f2bf(e0) | ((unsigned int)f2bf(e1) << 16);
}

// ---- prep: K [B,S,H,D] f32 -> Khi/Klo [B,H,S,D] bf16 (hi/lo split) ----
__global__ __launch_bounds__(256) void prep_k(const float* __restrict__ K,
                                              unsigned short* __restrict__ Khi,
                                              unsigned short* __restrict__ Klo) {
  int idx = blockIdx.x * 256 + threadIdx.x;       // 2^20 threads
  size_t f = (size_t)idx * 4;                     // dst flat index [B,H,S,D]
  int d  = (int)(f & 63);
  int s  = (int)((f >> 6) & 2047);
  int hh = (int)((f >> 17) & 15);
  int b  = (int)(f >> 21);
  const float* src = K + (((size_t)(b * S_LEN + s) * HEADS + hh) << 6) + d;
  f4v v = *(const f4v*)src;
  us4v hi, lo;
#pragma unroll
  for (int i = 0; i < 4; ++i) {
    unsigned short h = f2bf(v[i]);
    hi[i] = h;
    lo[i] = f2bf(v[i] - bf2f(h));
  }
  *(us4v*)(Khi + f) = hi;
  *(us4v*)(Klo + f) = lo;
}

// ---- prep: V [B,S,H,D] f32 -> Vt [B,H,D,S] bf16 (transpose + convert) ----
__global__ __launch_bounds__(256) void prep_v(const float* __restrict__ V,
                                              unsigned short* __restrict__ Vt) {
  int bh = blockIdx.x >> 5;
  int s0 = (blockIdx.x & 31) * 64;
  int b = bh >> 4, hh = bh & 15;
  int t = threadIdx.x;
  int sg = t & 15, dg = t >> 4;                   // 4x4 block per thread
  const float* base =
      V + (((size_t)(b * S_LEN + s0 + 4 * sg) * HEADS + hh) << 6) + 4 * dg;
  f4v r[4];
#pragma unroll
  for (int i = 0; i < 4; ++i) r[i] = *(const f4v*)(base + (size_t)i * (HEADS * DIM));
#pragma unroll
  for (int i2 = 0; i2 < 4; ++i2) {
    us4v w;
#pragma unroll
    for (int j = 0; j < 4; ++j) w[j] = f2bf(r[j][i2]);
    *(us4v*)(Vt + ((size_t)bh * DIM + 4 * dg + i2) * S_LEN + s0 + 4 * sg) = w;
  }
}

// ---- main: flash attention, 1 wave = 32 q rows, no LDS, no barriers ----
__global__ __launch_bounds__(256, 2) void attn_fwd(
    const float* __restrict__ Q, const float* __restrict__ MASK,
    const float* __restrict__ U, const unsigned short* __restrict__ Khi,
    const unsigned short* __restrict__ Klo, const unsigned short* __restrict__ Vt,
    float* __restrict__ OUT) {
  int bid = blockIdx.x;
  int lid = ((bid & 7) << 6) + (bid >> 3);        // XCD-bijective swizzle (512 blocks)
  int bh = lid >> 4, qt = lid & 15;
  int wv = threadIdx.x >> 6, ln = threadIdx.x & 63;
  int l31 = ln & 31, h5 = ln >> 5;
  int q = qt * 128 + wv * 32 + l31;
  int b = bh >> 4, hh = bh & 15;

  // Q B-fragments (hi/lo): B[n=q=lane&31][k=d = dc*16 + 8*h5 + j]
  const float* qrow = Q + (((size_t)(b * S_LEN + q) * HEADS + hh) << 6);
  s8v qfh[4], qfl[4];
#pragma unroll
  for (int dc = 0; dc < 4; ++dc) {
    const float* p = qrow + dc * 16 + 8 * h5;
    f4v va = *(const f4v*)p;
    f4v vb = *(const f4v*)(p + 4);
    u4v wh, wl;
#pragma unroll
    for (int t = 0; t < 4; ++t) {
      float x0 = (t < 2) ? va[2 * t] : vb[2 * (t - 2)];
      float x1 = (t < 2) ? va[2 * t + 1] : vb[2 * (t - 2) + 1];
      unsigned short h0 = f2bf(x0), h1 = f2bf(x1);
      wh[t] = (unsigned)h0 | ((unsigned)h1 << 16);
      wl[t] = pk2(x0 - bf2f(h0), x1 - bf2f(h1));
    }
    qfh[dc] = __builtin_bit_cast(s8v, wh);
    qfl[dc] = __builtin_bit_cast(s8v, wl);
  }

  const size_t mb = ((size_t)bh * S_LEN + q) * S_LEN;
  const float* mrow = MASK + mb;
  const float* urow = U + mb;
  const unsigned short* kbh = Khi + ((size_t)bh << 17);
  const unsigned short* kbl = Klo + ((size_t)bh << 17);
  const unsigned short* vbp = Vt + ((size_t)bh << 17);

  f16v o0, o1;
#pragma unroll
  for (int i = 0; i < 16; ++i) { o0[i] = 0.f; o1[i] = 0.f; }
  float mrun = -3.0e38f, lsum = 0.f;

  for (int kt = 0; kt < S_LEN / 32; ++kt) {
    int kv0 = kt << 5;
    // K A-fragments: A[m=kv=lane&31][k=d]
    s8v kfh[4], kfl[4];
#pragma unroll
    for (int dc = 0; dc < 4; ++dc) {
      size_t off = ((size_t)(kv0 + l31) << 6) + dc * 16 + 8 * h5;
      kfh[dc] = *(const s8v*)(kbh + off);
      kfl[dc] = *(const s8v*)(kbl + off);
    }
    // V^T A-fragments: A[m=d=lane&31 (+32)][k=kv]
    s8v vf0[2], vf1[2];
#pragma unroll
    for (int kc = 0; kc < 2; ++kc) {
      size_t o_ = ((size_t)l31 << 11) + (size_t)(kv0 + kc * 16 + 8 * h5);
      vf0[kc] = *(const s8v*)(vbp + o_);
      vf1[kc] = *(const s8v*)(vbp + ((size_t)32 << 11) + o_);
    }
    // mask / dropout fragments in S^T C-layout: k = kv0 + 8g + 4*h5 + i
    f4v mk[4], uk[4];
#pragma unroll
    for (int g = 0; g < 4; ++g) {
      int ko = kv0 + 8 * g + 4 * h5;
      mk[g] = *(const f4v*)(mrow + ko);
      uk[g] = *(const f4v*)(urow + ko);
    }
    // S^T = K·Q^T, fp32-accurate via hi/lo split
    f16v sc;
#pragma unroll
    for (int i = 0; i < 16; ++i) sc[i] = 0.f;
#pragma unroll
    for (int dc = 0; dc < 4; ++dc) {
      sc = __builtin_amdgcn_mfma_f32_32x32x16_bf16(kfh[dc], qfh[dc], sc, 0, 0, 0);
      sc = __builtin_amdgcn_mfma_f32_32x32x16_bf16(kfh[dc], qfl[dc], sc, 0, 0, 0);
      sc = __builtin_amdgcn_mfma_f32_32x32x16_bf16(kfl[dc], qfh[dc], sc, 0, 0, 0);
    }
    // scale (ref: scores / INV_SCALE = *8) + mask; online softmax
    float sv[16];
    float pmax = -3.0e38f;
#pragma unroll
    for (int r = 0; r < 16; ++r) {
      sv[r] = sc[r] * 8.0f + mk[r >> 2][r & 3];
      pmax = fmaxf(pmax, sv[r]);
    }
    pmax = fmaxf(pmax, __shfl_xor(pmax, 32));
    float mn = fmaxf(mrun, pmax);
    float al = __expf(mrun - mn);
    mrun = mn;
    lsum *= al;
#pragma unroll
    for (int i = 0; i < 16; ++i) { o0[i] *= al; o1[i] *= al; }
    float pv[16];
#pragma unroll
    for (int r = 0; r < 16; ++r) {
      pv[r] = __expf(sv[r] - mn);
      lsum += pv[r];   // denominator WITHOUT dropout (per reference)
    }
    // dropout + pack to bf16 pairs (own k = 8g + 4*h5 + {0..3})
    unsigned a0[4], a1[4];
#pragma unroll
    for (int g = 0; g < 4; ++g) {
      float d0 = (uk[g][0] >= 0.1f) ? pv[4 * g + 0] * (1.0f / 0.9f) : 0.f;
      float d1 = (uk[g][1] >= 0.1f) ? pv[4 * g + 1] * (1.0f / 0.9f) : 0.f;
      float d2 = (uk[g][2] >= 0.1f) ? pv[4 * g + 2] * (1.0f / 0.9f) : 0.f;
      float d3 = (uk[g][3] >= 0.1f) ? pv[4 * g + 3] * (1.0f / 0.9f) : 0.f;
      a0[g] = pk2(d0, d1);
      a1[g] = pk2(d2, d3);
    }
    // P^T B-fragments via half-wave exchange: B[k=kc*16+8*h5+j][n=q=lane&31]
    s8v pb[2];
#pragma unroll
    for (int kc = 0; kc < 2; ++kc) {
      unsigned x0 = a0[2 * kc], x1 = a0[2 * kc + 1];
      unsigned y0 = a1[2 * kc], y1 = a1[2 * kc + 1];
      unsigned sx0 = __shfl_xor(x0, 32), sx1 = __shfl_xor(x1, 32);
      unsigned sy0 = __shfl_xor(y0, 32), sy1 = __shfl_xor(y1, 32);
      u4v w;
      w[0] = h5 ? sx1 : x0;
      w[1] = h5 ? sy1 : y0;
      w[2] = h5 ? x1 : sx0;
      w[3] = h5 ? y1 : sy0;
      pb[kc] = __builtin_bit_cast(s8v, w);
    }
    // O^T += V^T · P^T
    o0 = __builtin_amdgcn_mfma_f32_32x32x16_bf16(vf0[0], pb[0], o0, 0, 0, 0);
    o0 = __builtin_amdgcn_mfma_f32_32x32x16_bf16(vf0[1], pb[1], o0, 0, 0, 0);
    o1 = __builtin_amdgcn_mfma_f32_32x32x16_bf16(vf1[0], pb[0], o1, 0, 0, 0);
    o1 = __builtin_amdgcn_mfma_f32_32x32x16_bf16(vf1[1], pb[1], o1, 0, 0, 0);
  }

  lsum += __shfl_xor(lsum, 32);
  float inv = 1.0f / lsum;
  // O^T C-layout: col = q = lane&31, row = d = 8g + 4*h5 + i (+32 for o1)
  float* orow = OUT + (((size_t)bh * S_LEN + q) << 6);
#pragma unroll
  for (int df = 0; df < 2; ++df) {
#pragma unroll
    for (int g = 0; g < 4; ++g) {
      f4v w;
#pragma unroll
      for (int i = 0; i < 4; ++i) w[i] = (df ? o1[4 * g + i] : o0[4 * g + i]) * inv;
      *(f4v*)(orow + df * 32 + 8 * g + 4 * h5) = w;
    }
  }
}

extern "C" void kernel_launch(void* const* d_in, const int* in_sizes, int n_in,
                              void* d_out, int out_size, void* d_ws, size_t ws_size,
                              hipStream_t stream) {
  const float* Q = (const float*)d_in[0];
  const float* K = (const float*)d_in[1];
  const float* V = (const float*)d_in[2];
  const float* M = (const float*)d_in[3];
  const float* U = (const float*)d_in[4];
  float* out = (float*)d_out;

  unsigned short* Khi = (unsigned short*)d_ws;              // 4M bf16 = 8 MB
  unsigned short* Klo = Khi + (size_t)(4u << 20);           // 8 MB
  unsigned short* Vt  = Klo + (size_t)(4u << 20);           // 8 MB (total 24 MB)

  prep_k<<<4096, 256, 0, stream>>>(K, Khi, Klo);
  prep_v<<<1024, 256, 0, stream>>>(V, Vt);
  attn_fwd<<<512, 256, 0, stream>>>(Q, M, U, Khi, Klo, Vt, out);
}